// Round 4
// baseline (1622.742 us; speedup 1.0000x reference)
//
#include <hip/hip_runtime.h>

#define B_ 4
#define S_ 1024
#define D_ 1024
#define F_ 4096
#define H_ 16
#define L_ 6
#define M_ (B_*S_)

typedef unsigned short u16;
typedef __attribute__((ext_vector_type(4))) unsigned short u16x4;
typedef __attribute__((ext_vector_type(8))) short s16x8;
typedef __attribute__((ext_vector_type(8))) __bf16 bf16x8;
typedef __attribute__((ext_vector_type(4))) float f32x4;

typedef const __attribute__((address_space(1))) unsigned int gu32;
typedef __attribute__((address_space(3))) unsigned int su32;

__device__ __forceinline__ u16 f2bf(float f) {
  union { float f; unsigned u; } v; v.f = f;
  unsigned u = v.u;
  return (u16)((u + 0x7fffu + ((u >> 16) & 1u)) >> 16);  // RNE
}

__device__ __forceinline__ f32x4 mfma16(s16x8 a, s16x8 b, f32x4 c) {
  return __builtin_amdgcn_mfma_f32_16x16x32_bf16(
      __builtin_bit_cast(bf16x8, a), __builtin_bit_cast(bf16x8, b), c, 0, 0, 0);
}

__device__ __forceinline__ void gload16(const void* g, void* s) {
  __builtin_amdgcn_global_load_lds((gu32*)g, (su32*)s, 16, 0, 0);
}

// swizzled LDS frag read: rows of 128B, byte ^= (row&7)<<4
__device__ __forceinline__ s16x8 readfrag(const u16* half, int r, int kk, int hi4) {
  const int c = (kk * 64 + hi4 * 16) ^ ((r & 7) << 4);
  return *(const s16x8*)((const char*)half + r * 128 + c);
}

// stage one 128x64 bf16 half-tile: linear LDS dest, inverse-swizzled global src
__device__ __forceinline__ void stage_half(
    const u16* __restrict__ src, int ldk, u16* lds_half, int w, int lane)
{
#pragma unroll
  for (int j = 0; j < 2; j++) {
    const int flat = j * 8192 + w * 1024 + lane * 16;   // byte in 16KB half
    const int row = flat >> 7;
    const int kb = (flat & 127) ^ ((row & 7) << 4);
    gload16(src + (size_t)row * ldk + (kb >> 1), lds_half + j * 4096 + w * 512);
  }
}

#define BAR     asm volatile("s_barrier" ::: "memory")
#define PH_PRE  asm volatile("s_barrier" ::: "memory"); __builtin_amdgcn_s_setprio(1)
#define PH_POST __builtin_amdgcn_s_setprio(0); __builtin_amdgcn_sched_barrier(0)
#define VM4     asm volatile("s_waitcnt vmcnt(4)" ::: "memory")
#define VM0     asm volatile("s_waitcnt vmcnt(0)" ::: "memory")

#define READ_B(bufhalf) do { \
  _Pragma("unroll") for (int nf = 0; nf < 4; nf++) \
  _Pragma("unroll") for (int kk = 0; kk < 2; kk++) \
    bfr[nf][kk] = readfrag(bufhalf, rb0 + nf * 16 + lo16, kk, hi4); } while (0)
#define READ_A(bufhalf, Q) do { \
  _Pragma("unroll") for (int m = 0; m < 2; m++) \
  _Pragma("unroll") for (int kk = 0; kk < 2; kk++) \
    af[m][kk] = readfrag(bufhalf, (2 * (Q) + m) * 16 + lo16, kk, hi4); } while (0)
#define DO_MFMA(Q) do { \
  _Pragma("unroll") for (int kk = 0; kk < 2; kk++) \
  _Pragma("unroll") for (int m = 0; m < 2; m++) \
  _Pragma("unroll") for (int nf = 0; nf < 4; nf++) \
    acc[2 * (Q) + m][nf] = mfma16(af[m][kk], bfr[nf][kk], acc[2 * (Q) + m][nf]); } while (0)

// ---------------- 256x256 8-phase GEMM: C = A[M,K] @ Bt[N,K]^T -------------
// Ring ledger (per wave, gload16 units; stage_half=2):
//   P0 ph0 stage A(2it+1) [it>0]  -> read this iter's P1  (RAW: P0 ph3 VM4)
//   P0 ph1/2 stage B(2it+2)       -> read next iter's P0  (RAW: P1 ph3 VM4)
//   P1 ph0 stage A(2it+2)         -> read next iter's P0  (RAW: P1 ph3 VM4)
//   P1 ph1/2 stage B(2it+3)       -> read next iter's P1  (RAW: next P0 ph3 VM4)
//   peeled P0 ph0 stage A(NT-1)   -> read peeled P1       (RAW: peeled VM0)
// WAR: every overwrite is issued after the barrier that follows the last
// MFMA consuming the old contents (MFMA pinned by sched_barrier(0)).
// OUTMODE 0: f32 partial (no bias)  1: bf16 (acc+bias)*scale  2: bf16 relu
template<int OUTMODE>
__device__ __forceinline__ void gemm256_body(
    const u16* __restrict__ A, const u16* __restrict__ Bt,
    const float* __restrict__ bias, float* __restrict__ Cf,
    u16* __restrict__ Ch, int N, int K, int kbeg, int kslice, float scale)
{
  __shared__ __align__(16) u16 As[2][2][8192];   // [parity][half][128x64]
  __shared__ __align__(16) u16 Bs[2][2][8192];
  const int tid = threadIdx.x, lane = tid & 63, w = tid >> 6;
  const int wr = w >> 2, wc = w & 3;
  const int lo16 = lane & 15, hi4 = lane >> 4;
  const int bm = blockIdx.x * 256, bn = blockIdx.y * 256;
  const int rb0 = (wc & 1) * 64;

  const u16* Abase = A + (size_t)bm * K + kbeg;
  const u16* Bbase = Bt + (size_t)bn * K + kbeg;
  const size_t h1 = (size_t)128 * K;
  const int NT = kslice >> 6, NI = NT >> 1;

  f32x4 acc[8][4];
#pragma unroll
  for (int i = 0; i < 8; i++)
#pragma unroll
    for (int j = 0; j < 4; j++) acc[i][j] = {0.f, 0.f, 0.f, 0.f};

  // prologue: tiles 0 (even) and 1 (odd)
  stage_half(Abase,           K, As[0][0], w, lane);
  stage_half(Abase + h1,      K, As[0][1], w, lane);
  stage_half(Bbase,           K, Bs[0][0], w, lane);
  stage_half(Bbase + h1,      K, Bs[0][1], w, lane);
  stage_half(Abase + 64,      K, As[1][0], w, lane);
  stage_half(Abase + h1 + 64, K, As[1][1], w, lane);
  stage_half(Bbase + 64,      K, Bs[1][0], w, lane);
  stage_half(Bbase + h1 + 64, K, Bs[1][1], w, lane);
  asm volatile("s_waitcnt vmcnt(8)" ::: "memory");   // tile 0 resident
  BAR;

  const u16* Ae = As[0][wr]; const u16* Ao = As[1][wr];
  const u16* Be = Bs[0][wc >> 1]; const u16* Bo = Bs[1][wc >> 1];
  s16x8 af[2][2], bfr[4][2];

  for (int it = 0; it < NI - 1; ++it) {
    // ---- parity 0: compute tile 2it ----
    READ_B(Be); READ_A(Ae, 0);
    if (it > 0) {                         // A(2it+1) both halves
      stage_half(Abase +      (size_t)(2 * it + 1) * 64, K, As[1][0], w, lane);
      stage_half(Abase + h1 + (size_t)(2 * it + 1) * 64, K, As[1][1], w, lane);
    }
    PH_PRE; DO_MFMA(0); PH_POST; BAR;
    READ_A(Ae, 1);
    stage_half(Bbase +      (size_t)(2 * it + 2) * 64, K, Bs[0][0], w, lane);
    PH_PRE; DO_MFMA(1); PH_POST; BAR;
    READ_A(Ae, 2);
    stage_half(Bbase + h1 + (size_t)(2 * it + 2) * 64, K, Bs[0][1], w, lane);
    PH_PRE; DO_MFMA(2); PH_POST; BAR;
    READ_A(Ae, 3);
    PH_PRE; DO_MFMA(3); PH_POST; VM4; BAR;
    // ---- parity 1: compute tile 2it+1 ----
    READ_B(Bo); READ_A(Ao, 0);
    stage_half(Abase +      (size_t)(2 * it + 2) * 64, K, As[0][0], w, lane);
    stage_half(Abase + h1 + (size_t)(2 * it + 2) * 64, K, As[0][1], w, lane);
    PH_PRE; DO_MFMA(0); PH_POST; BAR;
    READ_A(Ao, 1);
    stage_half(Bbase +      (size_t)(2 * it + 3) * 64, K, Bs[1][0], w, lane);
    PH_PRE; DO_MFMA(1); PH_POST; BAR;
    READ_A(Ao, 2);
    stage_half(Bbase + h1 + (size_t)(2 * it + 3) * 64, K, Bs[1][1], w, lane);
    PH_PRE; DO_MFMA(2); PH_POST; BAR;
    READ_A(Ao, 3);
    PH_PRE; DO_MFMA(3); PH_POST; VM4; BAR;
  }
  // peeled final iteration: tiles NT-2, NT-1.
  // FIX (round 3 bug): A(NT-1) was never staged by the ring — stage it here.
  READ_B(Be); READ_A(Ae, 0);
  stage_half(Abase +      (size_t)(NT - 1) * 64, K, As[1][0], w, lane);
  stage_half(Abase + h1 + (size_t)(NT - 1) * 64, K, As[1][1], w, lane);
  PH_PRE; DO_MFMA(0); PH_POST; BAR;
  READ_A(Ae, 1);             PH_PRE; DO_MFMA(1); PH_POST; BAR;
  READ_A(Ae, 2);             PH_PRE; DO_MFMA(2); PH_POST; BAR;
  READ_A(Ae, 3);             PH_PRE; DO_MFMA(3); PH_POST; VM0; BAR;
  READ_B(Bo); READ_A(Ao, 0); PH_PRE; DO_MFMA(0); PH_POST; BAR;
  READ_A(Ao, 1);             PH_PRE; DO_MFMA(1); PH_POST; BAR;
  READ_A(Ao, 2);             PH_PRE; DO_MFMA(2); PH_POST; BAR;
  READ_A(Ao, 3);             PH_PRE; DO_MFMA(3); PH_POST;

  // epilogue
  const int row0 = bm + wr * 128, col0 = bn + wc * 64;
#pragma unroll
  for (int nf = 0; nf < 4; nf++) {
    const int col = col0 + nf * 16 + lo16;
    const float bv = (OUTMODE == 0) ? 0.f : bias[col];
#pragma unroll
    for (int mf = 0; mf < 8; mf++) {
#pragma unroll
      for (int j = 0; j < 4; j++) {
        const int row = row0 + mf * 16 + hi4 * 4 + j;
        float v = acc[mf][nf][j];
        if (OUTMODE == 0) {
          Cf[(size_t)row * N + col] = v;
        } else {
          v = (v + bv) * scale;
          if (OUTMODE == 2) v = fmaxf(v, 0.f);
          Ch[(size_t)row * N + col] = f2bf(v);
        }
      }
    }
  }
}

__global__ __launch_bounds__(512, 2) void gemm_qkv(
    const u16* __restrict__ A, const u16* __restrict__ WT,
    const float* __restrict__ bq, const float* __restrict__ bk,
    const float* __restrict__ bv, u16* __restrict__ Out)
{
  const int z = blockIdx.z;
  const float* bias = (z == 0) ? bq : (z == 1) ? bk : bv;
  gemm256_body<1>(A, WT + (size_t)z * D_ * D_, bias, nullptr,
                  Out + (size_t)z * M_ * D_, D_, D_, 0, D_,
                  (z == 0) ? 0.125f : 1.0f);
}

__global__ __launch_bounds__(512, 2) void gemm_ffn1(
    const u16* __restrict__ A, const u16* __restrict__ WT,
    const float* __restrict__ bias, u16* __restrict__ Out)
{
  gemm256_body<2>(A, WT, bias, nullptr, Out, F_, D_, 0, D_, 1.0f);
}

__global__ __launch_bounds__(512, 2) void gemm_splitk4(
    const u16* __restrict__ A, const u16* __restrict__ WT,
    float* __restrict__ P, int N, int K)
{
  const int z = blockIdx.z;
  const int q = K >> 2;
  gemm256_body<0>(A, WT, nullptr, P + (size_t)z * M_ * (size_t)N, nullptr,
                  N, K, z * q, q, 1.0f);
}

// ---------------- weight transposes (f32 [R][C] -> bf16 [C][R]) ------------
__global__ __launch_bounds__(256) void transpose_cvt(
    const float* __restrict__ src, u16* __restrict__ dst, int R, int Cc)
{
  __shared__ float t[32][33];
  const int c0 = blockIdx.x * 32, r0 = blockIdx.y * 32;
  const int tx = threadIdx.x & 31, ty = threadIdx.x >> 5;
#pragma unroll
  for (int i = 0; i < 4; i++)
    t[ty + 8 * i][tx] = src[(size_t)(r0 + ty + 8 * i) * Cc + c0 + tx];
  __syncthreads();
#pragma unroll
  for (int i = 0; i < 4; i++)
    dst[(size_t)(c0 + ty + 8 * i) * R + r0 + tx] = f2bf(t[tx][ty + 8 * i]);
}

__global__ __launch_bounds__(256) void transpose4(
    const float* __restrict__ Wq, const float* __restrict__ Wk,
    const float* __restrict__ Wv, const float* __restrict__ Wo,
    u16* __restrict__ WTqkv, u16* __restrict__ WTo)
{
  __shared__ float t[32][33];
  const int z = blockIdx.z;
  const float* src = (z == 0) ? Wq : (z == 1) ? Wk : (z == 2) ? Wv : Wo;
  u16* dst = (z < 3) ? WTqkv + (size_t)z * D_ * D_ : WTo;
  const int c0 = blockIdx.x * 32, r0 = blockIdx.y * 32;
  const int tx = threadIdx.x & 31, ty = threadIdx.x >> 5;
#pragma unroll
  for (int i = 0; i < 4; i++)
    t[ty + 8 * i][tx] = src[(size_t)(r0 + ty + 8 * i) * D_ + c0 + tx];
  __syncthreads();
#pragma unroll
  for (int i = 0; i < 4; i++)
    dst[(size_t)(c0 + ty + 8 * i) * D_ + r0 + tx] = f2bf(t[tx][ty + 8 * i]);
}

// ---------------- V^T pre-pass ---------------------------------------------
__global__ __launch_bounds__(256) void vt_transpose(
    const u16* __restrict__ Vb, u16* __restrict__ Vt)
{
  __shared__ u16 t[64][66];
  const int s0 = blockIdx.x * 64;
  const int bh = blockIdx.y;
  const int b = bh >> 4, h = bh & 15;
  const int tid = threadIdx.x;
  const int row = tid >> 2;
  const int c0 = (tid & 3) * 16;
  const u16* src = Vb + (size_t)(b * S_ + s0 + row) * D_ + h * 64 + c0;
  *(s16x8*)&t[row][c0] = *(const s16x8*)src;
  *(s16x8*)&t[row][c0 + 8] = *(const s16x8*)(src + 8);
  __syncthreads();
  const int dh = tid >> 2;
  const int sc = (tid & 3) * 16;
  s16x8 a, bv;
#pragma unroll
  for (int u = 0; u < 8; u++) a[u] = (short)t[sc + u][dh];
#pragma unroll
  for (int u = 0; u < 8; u++) bv[u] = (short)t[sc + 8 + u][dh];
  u16* dst = Vt + (size_t)(bh * 64 + dh) * S_ + s0 + sc;
  *(s16x8*)dst = a;
  *(s16x8*)(dst + 8) = bv;
}

// ---------------- flash attention ------------------------------------------
__device__ __forceinline__ s16x8 lds_swz(const u16* base, int row, int cb) {
  const int addr = row * 128 + (cb ^ ((row & 7) << 4));
  return *(const s16x8*)((const char*)base + addr);
}

__global__ __launch_bounds__(256, 4) void attn_kernel(
    const u16* __restrict__ Qb, const u16* __restrict__ Kb,
    const u16* __restrict__ Vt, const int* __restrict__ mask,
    const float* __restrict__ rb, u16* __restrict__ AO)
{
  __shared__ float lut[2048];
  __shared__ __align__(16) u16 Ks[64 * 64];
  __shared__ __align__(16) u16 Vs[64 * 64];
  __shared__ __align__(16) u16 Ps[4][16 * 68];

  const int tid = threadIdx.x;
  const int lane = tid & 63;
  const int w = tid >> 6;
  const int bh = blockIdx.x;
  const int b = bh >> 4, h = bh & 15;
  const int q0 = blockIdx.y * 64 + w * 16;
  const int bS = b * S_, hh = h * 64;

  for (int idx = tid; idx < 2048; idx += 256) {
    const int rel = idx - 1024;
    const int ret = rel < 0 ? 16 : 0;
    const int n = rel < 0 ? -rel : rel;
    int bu;
    if (n < 8) bu = ret + n;
    else {
      const float t = logf((float)n * 0.125f) * (8.0f / 3.4657359027997265f);
      int vl = 8 + (int)t;
      if (vl > 15) vl = 15;
      bu = ret + vl;
    }
    lut[idx] = rb[bu * 16 + h] * 8.0f;
  }

  s16x8 qf[2];
#pragma unroll
  for (int kk = 0; kk < 2; kk++)
    qf[kk] = *(const s16x8*)(Qb + (size_t)(bS + q0 + (lane & 15)) * D_ + hh +
                             kk * 32 + (lane >> 4) * 8);

  f32x4 oacc[4];
#pragma unroll
  for (int i = 0; i < 4; i++) oacc[i] = {0.f, 0.f, 0.f, 0.f};
  float rm[4], rl[4];
#pragma unroll
  for (int j = 0; j < 4; j++) { rm[j] = -3e38f; rl[j] = 0.f; }

  for (int kt = 0; kt < S_; kt += 64) {
    __syncthreads();
#pragma unroll
    for (int i = 0; i < 2; i++) {
      const int flat = i * 4096 + w * 1024 + lane * 16;
      const int row = flat >> 7;
      const int ce = ((flat & 127) ^ ((row & 7) << 4)) >> 1;
      gload16(Kb + (size_t)(bS + kt + row) * D_ + hh + ce, Ks + i * 2048 + w * 512);
      gload16(Vt + (size_t)(bh * 64 + row) * S_ + kt + ce, Vs + i * 2048 + w * 512);
    }
    __syncthreads();

    f32x4 sacc[4];
#pragma unroll
    for (int i = 0; i < 4; i++) sacc[i] = {0.f, 0.f, 0.f, 0.f};
#pragma unroll
    for (int kk = 0; kk < 2; kk++) {
      const int cb = kk * 64 + (lane >> 4) * 16;
#pragma unroll
      for (int nf = 0; nf < 4; nf++) {
        const s16x8 kb = lds_swz(Ks, nf * 16 + (lane & 15), cb);
        sacc[nf] = mfma16(qf[kk], kb, sacc[nf]);
      }
    }

    int km[4];
#pragma unroll
    for (int nf = 0; nf < 4; nf++)
      km[nf] = mask[bS + kt + nf * 16 + (lane & 15)];

    const int lidx0 = q0 + (lane >> 4) * 4 + 1024 - kt - (lane & 15);
#pragma unroll
    for (int j = 0; j < 4; j++) {
      const int lrow = ((lane >> 4) << 2) + j;
      float sc[4];
      float mx = -3e38f;
#pragma unroll
      for (int nf = 0; nf < 4; nf++) {
        float s = (km[nf] == 0) ? -1e10f : sacc[nf][j];
        s += lut[lidx0 + j - nf * 16];
        sc[nf] = s;
        mx = fmaxf(mx, s);
      }
      mx = fmaxf(mx, __shfl_xor(mx, 1));
      mx = fmaxf(mx, __shfl_xor(mx, 2));
      mx = fmaxf(mx, __shfl_xor(mx, 4));
      mx = fmaxf(mx, __shfl_xor(mx, 8));
      const float m_new = fmaxf(rm[j], mx);
      const float fs = __expf(rm[j] - m_new);
      rm[j] = m_new;
      float psum = 0.f;
#pragma unroll
      for (int nf = 0; nf < 4; nf++) {
        const float p = __expf(sc[nf] - m_new);
        psum += p;
        Ps[w][lrow * 68 + nf * 16 + (lane & 15)] = f2bf(p);
      }
      psum += __shfl_xor(psum, 1);
      psum += __shfl_xor(psum, 2);
      psum += __shfl_xor(psum, 4);
      psum += __shfl_xor(psum, 8);
      rl[j] = rl[j] * fs + psum;
#pragma unroll
      for (int df = 0; df < 4; df++) oacc[df][j] *= fs;
    }

#pragma unroll
    for (int kk = 0; kk < 2; kk++) {
      const s16x8 pa = *(const s16x8*)&Ps[w][(lane & 15) * 68 + kk * 32 + (lane >> 4) * 8];
      const int cb = kk * 64 + (lane >> 4) * 16;
#pragma unroll
      for (int df = 0; df < 4; df++) {
        const s16x8 vb = lds_swz(Vs, df * 16 + (lane & 15), cb);
        oacc[df] = mfma16(pa, vb, oacc[df]);
      }
    }
  }

  float inv[4];
#pragma unroll
  for (int j = 0; j < 4; j++) inv[j] = 1.0f / rl[j];
#pragma unroll
  for (int df = 0; df < 4; df++)
#pragma unroll
    for (int j = 0; j < 4; j++) {
      const int qrow = q0 + ((lane >> 4) << 2) + j;
      AO[(size_t)(bS + qrow) * D_ + hh + df * 16 + (lane & 15)] =
          f2bf(oacc[df][j] * inv[j]);
    }
}

// ---------------- fused: Y = LN(X + P0+P1+P2+P3 + bias) --------------------
__global__ __launch_bounds__(256) void ln_fused4(
    const float* __restrict__ X, const float* __restrict__ P,
    const float* __restrict__ bias, const float* __restrict__ g,
    const float* __restrict__ be, float* __restrict__ Yf, u16* __restrict__ Yh)
{
  const int row = blockIdx.x;
  const int tid = threadIdx.x;
  const size_t off = (size_t)row * D_;
  const size_t pstride = (size_t)M_ * D_;
  const float4 xv = ((const float4*)(X + off))[tid];
  const float4 p0 = ((const float4*)(P + off))[tid];
  const float4 p1 = ((const float4*)(P + pstride + off))[tid];
  const float4 p2 = ((const float4*)(P + 2 * pstride + off))[tid];
  const float4 p3 = ((const float4*)(P + 3 * pstride + off))[tid];
  const float4 bb = ((const float4*)bias)[tid];
  const float v0 = xv.x + p0.x + p1.x + p2.x + p3.x + bb.x;
  const float v1 = xv.y + p0.y + p1.y + p2.y + p3.y + bb.y;
  const float v2 = xv.z + p0.z + p1.z + p2.z + p3.z + bb.z;
  const float v3 = xv.w + p0.w + p1.w + p2.w + p3.w + bb.w;
  float sum = v0 + v1 + v2 + v3;
  float ss = v0 * v0 + v1 * v1 + v2 * v2 + v3 * v3;
#pragma unroll
  for (int o = 1; o < 64; o <<= 1) {
    sum += __shfl_xor(sum, o);
    ss += __shfl_xor(ss, o);
  }
  __shared__ float s1[4], s2[4];
  if ((tid & 63) == 0) { s1[tid >> 6] = sum; s2[tid >> 6] = ss; }
  __syncthreads();
  sum = s1[0] + s1[1] + s1[2] + s1[3];
  ss = s2[0] + s2[1] + s2[2] + s2[3];
  const float mu = sum * (1.f / D_);
  const float var = ss * (1.f / D_) - mu * mu;
  const float rstd = rsqrtf(var + 1e-5f);
  const float4 gv = ((const float4*)g)[tid];
  const float4 bv = ((const float4*)be)[tid];
  float4 y;
  y.x = (v0 - mu) * rstd * gv.x + bv.x;
  y.y = (v1 - mu) * rstd * gv.y + bv.y;
  y.z = (v2 - mu) * rstd * gv.z + bv.z;
  y.w = (v3 - mu) * rstd * gv.w + bv.w;
  ((float4*)(Yf + off))[tid] = y;
  u16x4 hv;
  hv.x = f2bf(y.x); hv.y = f2bf(y.y); hv.z = f2bf(y.z); hv.w = f2bf(y.w);
  ((u16x4*)(Yh + off))[tid] = hv;
}

// ---------------- embedding -------------------------------------------------
__global__ __launch_bounds__(256) void embed_kernel(
    const int* __restrict__ src, const float* __restrict__ tok,
    const float* __restrict__ pos, float* __restrict__ X, u16* __restrict__ Xh)
{
  const int row = blockIdx.x;
  const int s = row & (S_ - 1);
  const int t = src[row];
  const int tid = threadIdx.x;
  const float4 tv = ((const float4*)(tok + (size_t)t * D_))[tid];
  const float4 pv = ((const float4*)(pos + (size_t)s * D_))[tid];
  float4 y;
  y.x = tv.x * 32.f + pv.x;
  y.y = tv.y * 32.f + pv.y;
  y.z = tv.z * 32.f + pv.z;
  y.w = tv.w * 32.f + pv.w;
  ((float4*)(X + (size_t)row * D_))[tid] = y;
  u16x4 hv;
  hv.x = f2bf(y.x); hv.y = f2bf(y.y); hv.z = f2bf(y.z); hv.w = f2bf(y.w);
  ((u16x4*)(Xh + (size_t)row * D_))[tid] = hv;
}

// ---------------- launch ----------------------------------------------------
extern "C" void kernel_launch(void* const* d_in, const int* in_sizes, int n_in,
                              void* d_out, int out_size, void* d_ws, size_t ws_size,
                              hipStream_t stream)
{
  const int* src = (const int*)d_in[0];
  const int* mask = (const int*)d_in[1];
  const float* tok_emb = (const float*)d_in[2];
  const float* pos_emb = (const float*)d_in[3];
  const float* Wq = (const float*)d_in[4];
  const float* bq = (const float*)d_in[5];
  const float* Wk = (const float*)d_in[6];
  const float* bk = (const float*)d_in[7];
  const float* Wv = (const float*)d_in[8];
  const float* bv = (const float*)d_in[9];
  const float* Wo = (const float*)d_in[10];
  const float* bo = (const float*)d_in[11];
  const float* rb = (const float*)d_in[12];
  const float* g1 = (const float*)d_in[13];
  const float* b1n = (const float*)d_in[14];
  const float* W1 = (const float*)d_in[15];
  const float* b1f = (const float*)d_in[16];
  const float* W2 = (const float*)d_in[17];
  const float* b2f = (const float*)d_in[18];
  const float* g2 = (const float*)d_in[19];
  const float* b2n = (const float*)d_in[20];
  float* out = (float*)d_out;

  // ws map (152 MB peak):
  //   0-16  xb f32      16-24 xb16      24-32 Qb16    32-40 Kb16
  //  40-48  Vb16        48-56 Vt16      56-64 AO16
  //  24-56  Hb16 (reuses dead Q/K/V/Vt region during FFN)
  //  64-128 Pp (4x16MB f32 split-K partials)
  // 128-134 WTqkv  134-136 WTo  136-144 WT1  144-152 WT2
  char* ws = (char*)d_ws;
  const size_t MB = 1ull << 20;
  float* xb   = (float*)(ws + 0);
  u16*   xb16 = (u16*)(ws + 16 * MB);
  u16*   Qb16 = (u16*)(ws + 24 * MB);
  u16*   Kb16 = (u16*)(ws + 32 * MB);
  u16*   Vb16 = (u16*)(ws + 40 * MB);
  u16*   Vt16 = (u16*)(ws + 48 * MB);
  u16*   AO16 = (u16*)(ws + 56 * MB);
  float* Pp   = (float*)(ws + 64 * MB);
  u16*   WTqkv= (u16*)(ws + 128 * MB);
  u16*   WTo  = (u16*)(ws + 134 * MB);
  u16*   WT1  = (u16*)(ws + 136 * MB);
  u16*   WT2  = (u16*)(ws + 144 * MB);
  u16*   Hb16 = (u16*)(ws + 24 * MB);

  embed_kernel<<<M_, 256, 0, stream>>>(src, tok_emb, pos_emb, xb, xb16);

  for (int l = 0; l < L_; l++) {
    const size_t oDD = (size_t)l * D_ * D_;
    const size_t oDF = (size_t)l * D_ * F_;

    transpose4<<<dim3(32, 32, 4), 256, 0, stream>>>(
        Wq + oDD, Wk + oDD, Wv + oDD, Wo + oDD, WTqkv, WTo);
    transpose_cvt<<<dim3(F_ / 32, D_ / 32), 256, 0, stream>>>(W1 + oDF, WT1, D_, F_);
    transpose_cvt<<<dim3(D_ / 32, F_ / 32), 256, 0, stream>>>(W2 + oDF, WT2, F_, D_);

    gemm_qkv<<<dim3(M_ / 256, D_ / 256, 3), 512, 0, stream>>>(
        xb16, WTqkv, bq + l * D_, bk + l * D_, bv + l * D_, Qb16);

    vt_transpose<<<dim3(S_ / 64, B_ * H_), 256, 0, stream>>>(Vb16, Vt16);

    attn_kernel<<<dim3(B_ * H_, S_ / 64), 256, 0, stream>>>(
        Qb16, Kb16, Vt16, mask, rb + l * 32 * H_, AO16);

    gemm_splitk4<<<dim3(M_ / 256, D_ / 256, 4), 512, 0, stream>>>(
        AO16, WTo, Pp, D_, D_);

    ln_fused4<<<M_, 256, 0, stream>>>(
        xb, Pp, bo + l * D_, g1 + l * D_, b1n + l * D_, xb, xb16);

    gemm_ffn1<<<dim3(M_ / 256, F_ / 256), 512, 0, stream>>>(
        xb16, WT1, b1f + l * F_, Hb16);

    gemm_splitk4<<<dim3(M_ / 256, D_ / 256, 4), 512, 0, stream>>>(
        Hb16, WT2, Pp, D_, F_);

    ln_fused4<<<M_, 256, 0, stream>>>(
        xb, Pp, b2f + l * D_, g2 + l * D_, b2n + l * D_,
        (l == L_ - 1) ? out : xb, xb16);
  }
}

// Round 5
// 1514.585 us; speedup vs baseline: 1.0714x; 1.0714x over previous
//
#include <hip/hip_runtime.h>

#define B_ 4
#define S_ 1024
#define D_ 1024
#define F_ 4096
#define H_ 16
#define L_ 6
#define M_ (B_*S_)

typedef unsigned short u16;
typedef __attribute__((ext_vector_type(4))) unsigned short u16x4;
typedef __attribute__((ext_vector_type(8))) short s16x8;
typedef __attribute__((ext_vector_type(8))) __bf16 bf16x8;
typedef __attribute__((ext_vector_type(4))) float f32x4;

typedef const __attribute__((address_space(1))) unsigned int gu32;
typedef __attribute__((address_space(3))) unsigned int su32;

__device__ __forceinline__ u16 f2bf(float f) {
  union { float f; unsigned u; } v; v.f = f;
  unsigned u = v.u;
  return (u16)((u + 0x7fffu + ((u >> 16) & 1u)) >> 16);  // RNE
}

__device__ __forceinline__ f32x4 mfma16(s16x8 a, s16x8 b, f32x4 c) {
  return __builtin_amdgcn_mfma_f32_16x16x32_bf16(
      __builtin_bit_cast(bf16x8, a), __builtin_bit_cast(bf16x8, b), c, 0, 0, 0);
}

__device__ __forceinline__ void gload16(const void* g, void* s) {
  __builtin_amdgcn_global_load_lds((gu32*)g, (su32*)s, 16, 0, 0);
}

// ============ 128x128 m97-structure GEMM (2-barrier, linear LDS) ============
// OUTMODE 0: f32 partial (no bias)   3: fused-QKV bf16 out, z=col>>10
template<int OUTMODE>
__device__ __forceinline__ void gemm128_body(
    const u16* __restrict__ A, const u16* __restrict__ Bt,
    const float* __restrict__ bias, float* __restrict__ Cf,
    u16* __restrict__ Ch, int N, int K, int kbeg, int kend,
    const float* __restrict__ bias2, const float* __restrict__ bias3)
{
  __shared__ __align__(16) u16 As[128 * 64];
  __shared__ __align__(16) u16 Bs[128 * 64];
  const int tid = threadIdx.x, lane = tid & 63, w = tid >> 6;
  const int bm = blockIdx.x * 128, bn = blockIdx.y * 128;
  const int wm = (w >> 1) * 64, wn = (w & 1) * 64;

  f32x4 acc[4][4];
#pragma unroll
  for (int i = 0; i < 4; i++)
#pragma unroll
    for (int j = 0; j < 4; j++) acc[i][j] = {0.f, 0.f, 0.f, 0.f};

  for (int k0 = kbeg; k0 < kend; k0 += 64) {
    __syncthreads();
#pragma unroll
    for (int i = 0; i < 4; i++) {
      const int flat = i * 4096 + w * 1024 + lane * 16;  // bytes in tile
      const int row = flat >> 7, ce = (flat & 127) >> 1;
      gload16(A + (size_t)(bm + row) * K + k0 + ce, As + i * 2048 + w * 512);
      gload16(Bt + (size_t)(bn + row) * K + k0 + ce, Bs + i * 2048 + w * 512);
    }
    __syncthreads();
#pragma unroll
    for (int kk = 0; kk < 2; kk++) {
      s16x8 af[4], bf[4];
#pragma unroll
      for (int mf = 0; mf < 4; mf++)
        af[mf] = *(const s16x8*)&As[(wm + mf * 16 + (lane & 15)) * 64 + kk * 32 + (lane >> 4) * 8];
#pragma unroll
      for (int nf = 0; nf < 4; nf++)
        bf[nf] = *(const s16x8*)&Bs[(wn + nf * 16 + (lane & 15)) * 64 + kk * 32 + (lane >> 4) * 8];
#pragma unroll
      for (int mf = 0; mf < 4; mf++)
#pragma unroll
        for (int nf = 0; nf < 4; nf++)
          acc[mf][nf] = mfma16(af[mf], bf[nf], acc[mf][nf]);
    }
  }
#pragma unroll
  for (int nf = 0; nf < 4; nf++) {
    const int col = bn + wn + nf * 16 + (lane & 15);
    float bvv = 0.f, sc = 1.0f;
    int zz = 0, lc = col;
    if (OUTMODE == 3) {
      zz = col >> 10; lc = col & 1023;
      const float* bp = (zz == 0) ? bias : (zz == 1) ? bias2 : bias3;
      bvv = bp[lc];
      sc = (zz == 0) ? 0.125f : 1.0f;
    }
#pragma unroll
    for (int mf = 0; mf < 4; mf++) {
#pragma unroll
      for (int j = 0; j < 4; j++) {
        const int row = bm + wm + mf * 16 + ((lane >> 4) << 2) + j;
        const float v = acc[mf][nf][j];
        if (OUTMODE == 0) {
          Cf[(size_t)row * N + col] = v;
        } else {
          Ch[(size_t)zz * M_ * D_ + (size_t)row * D_ + lc] = f2bf((v + bvv) * sc);
        }
      }
    }
  }
}

// fused QKV: Bt = [WTq;WTk;WTv] rows 0..3071, out = contiguous Q|K|V bf16
__global__ __launch_bounds__(256, 3) void gemm_qkvf(
    const u16* __restrict__ A, const u16* __restrict__ WT,
    const float* __restrict__ bq, const float* __restrict__ bk,
    const float* __restrict__ bv, u16* __restrict__ Out)
{
  gemm128_body<3>(A, WT, bq, nullptr, Out, 3 * D_, D_, 0, D_, bk, bv);
}

__global__ __launch_bounds__(256, 3) void gemm_splitk2(
    const u16* __restrict__ A, const u16* __restrict__ WT,
    float* __restrict__ P, int N, int K)
{
  const int z = blockIdx.z;
  const int half = K >> 1;
  gemm128_body<0>(A, WT, nullptr, P + (size_t)z * M_ * (size_t)N, nullptr,
                  N, K, z * half, z * half + half, nullptr, nullptr);
}

// ============ 256x256 8-phase GEMM (round-4-verified, peel-fixed) ===========
__device__ __forceinline__ s16x8 readfrag(const u16* half, int r, int kk, int hi4) {
  const int c = (kk * 64 + hi4 * 16) ^ ((r & 7) << 4);
  return *(const s16x8*)((const char*)half + r * 128 + c);
}

__device__ __forceinline__ void stage_half(
    const u16* __restrict__ src, int ldk, u16* lds_half, int w, int lane)
{
#pragma unroll
  for (int j = 0; j < 2; j++) {
    const int flat = j * 8192 + w * 1024 + lane * 16;   // byte in 16KB half
    const int row = flat >> 7;
    const int kb = (flat & 127) ^ ((row & 7) << 4);
    gload16(src + (size_t)row * ldk + (kb >> 1), lds_half + j * 4096 + w * 512);
  }
}

#define BAR     asm volatile("s_barrier" ::: "memory")
#define PH_PRE  asm volatile("s_barrier" ::: "memory"); __builtin_amdgcn_s_setprio(1)
#define PH_POST __builtin_amdgcn_s_setprio(0); __builtin_amdgcn_sched_barrier(0)
#define VM4     asm volatile("s_waitcnt vmcnt(4)" ::: "memory")
#define VM0     asm volatile("s_waitcnt vmcnt(0)" ::: "memory")

#define READ_B(bufhalf) do { \
  _Pragma("unroll") for (int nf = 0; nf < 4; nf++) \
  _Pragma("unroll") for (int kk = 0; kk < 2; kk++) \
    bfr[nf][kk] = readfrag(bufhalf, rb0 + nf * 16 + lo16, kk, hi4); } while (0)
#define READ_A(bufhalf, Q) do { \
  _Pragma("unroll") for (int m = 0; m < 2; m++) \
  _Pragma("unroll") for (int kk = 0; kk < 2; kk++) \
    af[m][kk] = readfrag(bufhalf, (2 * (Q) + m) * 16 + lo16, kk, hi4); } while (0)
#define DO_MFMA(Q) do { \
  _Pragma("unroll") for (int kk = 0; kk < 2; kk++) \
  _Pragma("unroll") for (int m = 0; m < 2; m++) \
  _Pragma("unroll") for (int nf = 0; nf < 4; nf++) \
    acc[2 * (Q) + m][nf] = mfma16(af[m][kk], bfr[nf][kk], acc[2 * (Q) + m][nf]); } while (0)

// FFN1 only: C[M,F] = relu(A[M,D] @ WT[F,D]^T + bias), bf16 out
__global__ __launch_bounds__(512, 2) void gemm_ffn1(
    const u16* __restrict__ A, const u16* __restrict__ Bt,
    const float* __restrict__ bias, u16* __restrict__ Ch)
{
  __shared__ __align__(16) u16 As[2][2][8192];   // [parity][half][128x64]
  __shared__ __align__(16) u16 Bs[2][2][8192];
  const int tid = threadIdx.x, lane = tid & 63, w = tid >> 6;
  const int wr = w >> 2, wc = w & 3;
  const int lo16 = lane & 15, hi4 = lane >> 4;
  const int bm = blockIdx.x * 256, bn = blockIdx.y * 256;
  const int rb0 = (wc & 1) * 64;
  const int K = D_, N = F_;

  const u16* Abase = A + (size_t)bm * K;
  const u16* Bbase = Bt + (size_t)bn * K;
  const size_t h1 = (size_t)128 * K;
  const int NT = K >> 6, NI = NT >> 1;

  f32x4 acc[8][4];
#pragma unroll
  for (int i = 0; i < 8; i++)
#pragma unroll
    for (int j = 0; j < 4; j++) acc[i][j] = {0.f, 0.f, 0.f, 0.f};

  stage_half(Abase,           K, As[0][0], w, lane);
  stage_half(Abase + h1,      K, As[0][1], w, lane);
  stage_half(Bbase,           K, Bs[0][0], w, lane);
  stage_half(Bbase + h1,      K, Bs[0][1], w, lane);
  stage_half(Abase + 64,      K, As[1][0], w, lane);
  stage_half(Abase + h1 + 64, K, As[1][1], w, lane);
  stage_half(Bbase + 64,      K, Bs[1][0], w, lane);
  stage_half(Bbase + h1 + 64, K, Bs[1][1], w, lane);
  asm volatile("s_waitcnt vmcnt(8)" ::: "memory");
  BAR;

  const u16* Ae = As[0][wr]; const u16* Ao = As[1][wr];
  const u16* Be = Bs[0][wc >> 1]; const u16* Bo = Bs[1][wc >> 1];
  s16x8 af[2][2], bfr[4][2];

  for (int it = 0; it < NI - 1; ++it) {
    READ_B(Be); READ_A(Ae, 0);
    if (it > 0) {
      stage_half(Abase +      (size_t)(2 * it + 1) * 64, K, As[1][0], w, lane);
      stage_half(Abase + h1 + (size_t)(2 * it + 1) * 64, K, As[1][1], w, lane);
    }
    PH_PRE; DO_MFMA(0); PH_POST; BAR;
    READ_A(Ae, 1);
    stage_half(Bbase +      (size_t)(2 * it + 2) * 64, K, Bs[0][0], w, lane);
    PH_PRE; DO_MFMA(1); PH_POST; BAR;
    READ_A(Ae, 2);
    stage_half(Bbase + h1 + (size_t)(2 * it + 2) * 64, K, Bs[0][1], w, lane);
    PH_PRE; DO_MFMA(2); PH_POST; BAR;
    READ_A(Ae, 3);
    PH_PRE; DO_MFMA(3); PH_POST; VM4; BAR;
    READ_B(Bo); READ_A(Ao, 0);
    stage_half(Abase +      (size_t)(2 * it + 2) * 64, K, As[0][0], w, lane);
    stage_half(Abase + h1 + (size_t)(2 * it + 2) * 64, K, As[0][1], w, lane);
    PH_PRE; DO_MFMA(0); PH_POST; BAR;
    READ_A(Ao, 1);
    stage_half(Bbase +      (size_t)(2 * it + 3) * 64, K, Bs[1][0], w, lane);
    PH_PRE; DO_MFMA(1); PH_POST; BAR;
    READ_A(Ao, 2);
    stage_half(Bbase + h1 + (size_t)(2 * it + 3) * 64, K, Bs[1][1], w, lane);
    PH_PRE; DO_MFMA(2); PH_POST; BAR;
    READ_A(Ao, 3);
    PH_PRE; DO_MFMA(3); PH_POST; VM4; BAR;
  }
  // peeled final iteration (A(NT-1) staged here — round-3 bugfix retained)
  READ_B(Be); READ_A(Ae, 0);
  stage_half(Abase +      (size_t)(NT - 1) * 64, K, As[1][0], w, lane);
  stage_half(Abase + h1 + (size_t)(NT - 1) * 64, K, As[1][1], w, lane);
  PH_PRE; DO_MFMA(0); PH_POST; BAR;
  READ_A(Ae, 1);             PH_PRE; DO_MFMA(1); PH_POST; BAR;
  READ_A(Ae, 2);             PH_PRE; DO_MFMA(2); PH_POST; BAR;
  READ_A(Ae, 3);             PH_PRE; DO_MFMA(3); PH_POST; VM0; BAR;
  READ_B(Bo); READ_A(Ao, 0); PH_PRE; DO_MFMA(0); PH_POST; BAR;
  READ_A(Ao, 1);             PH_PRE; DO_MFMA(1); PH_POST; BAR;
  READ_A(Ao, 2);             PH_PRE; DO_MFMA(2); PH_POST; BAR;
  READ_A(Ao, 3);             PH_PRE; DO_MFMA(3); PH_POST;

  const int row0 = bm + wr * 128, col0 = bn + wc * 64;
#pragma unroll
  for (int nf = 0; nf < 4; nf++) {
    const int col = col0 + nf * 16 + lo16;
    const float bv = bias[col];
#pragma unroll
    for (int mf = 0; mf < 8; mf++) {
#pragma unroll
      for (int j = 0; j < 4; j++) {
        const int row = row0 + mf * 16 + hi4 * 4 + j;
        Ch[(size_t)row * N + col] = f2bf(fmaxf(acc[mf][nf][j] + bv, 0.f));
      }
    }
  }
}

// ---------------- weight transposes (f32 [R][C] -> bf16 [C][R]) ------------
__global__ __launch_bounds__(256) void transpose_cvt(
    const float* __restrict__ src, u16* __restrict__ dst, int R, int Cc)
{
  __shared__ float t[32][33];
  const int c0 = blockIdx.x * 32, r0 = blockIdx.y * 32;
  const int tx = threadIdx.x & 31, ty = threadIdx.x >> 5;
#pragma unroll
  for (int i = 0; i < 4; i++)
    t[ty + 8 * i][tx] = src[(size_t)(r0 + ty + 8 * i) * Cc + c0 + tx];
  __syncthreads();
#pragma unroll
  for (int i = 0; i < 4; i++)
    dst[(size_t)(c0 + ty + 8 * i) * R + r0 + tx] = f2bf(t[tx][ty + 8 * i]);
}

__global__ __launch_bounds__(256) void transpose4(
    const float* __restrict__ Wq, const float* __restrict__ Wk,
    const float* __restrict__ Wv, const float* __restrict__ Wo,
    u16* __restrict__ WTqkv, u16* __restrict__ WTo)
{
  __shared__ float t[32][33];
  const int z = blockIdx.z;
  const float* src = (z == 0) ? Wq : (z == 1) ? Wk : (z == 2) ? Wv : Wo;
  u16* dst = (z < 3) ? WTqkv + (size_t)z * D_ * D_ : WTo;
  const int c0 = blockIdx.x * 32, r0 = blockIdx.y * 32;
  const int tx = threadIdx.x & 31, ty = threadIdx.x >> 5;
#pragma unroll
  for (int i = 0; i < 4; i++)
    t[ty + 8 * i][tx] = src[(size_t)(r0 + ty + 8 * i) * D_ + c0 + tx];
  __syncthreads();
#pragma unroll
  for (int i = 0; i < 4; i++)
    dst[(size_t)(c0 + ty + 8 * i) * D_ + r0 + tx] = f2bf(t[tx][ty + 8 * i]);
}

// ---------------- V^T pre-pass ---------------------------------------------
__global__ __launch_bounds__(256) void vt_transpose(
    const u16* __restrict__ Vb, u16* __restrict__ Vt)
{
  __shared__ u16 t[64][66];
  const int s0 = blockIdx.x * 64;
  const int bh = blockIdx.y;
  const int b = bh >> 4, h = bh & 15;
  const int tid = threadIdx.x;
  const int row = tid >> 2;
  const int c0 = (tid & 3) * 16;
  const u16* src = Vb + (size_t)(b * S_ + s0 + row) * D_ + h * 64 + c0;
  *(s16x8*)&t[row][c0] = *(const s16x8*)src;
  *(s16x8*)&t[row][c0 + 8] = *(const s16x8*)(src + 8);
  __syncthreads();
  const int dh = tid >> 2;
  const int sc = (tid & 3) * 16;
  s16x8 a, bv;
#pragma unroll
  for (int u = 0; u < 8; u++) a[u] = (short)t[sc + u][dh];
#pragma unroll
  for (int u = 0; u < 8; u++) bv[u] = (short)t[sc + 8 + u][dh];
  u16* dst = Vt + (size_t)(bh * 64 + dh) * S_ + s0 + sc;
  *(s16x8*)dst = a;
  *(s16x8*)(dst + 8) = bv;
}

// ---------------- flash attention ------------------------------------------
__device__ __forceinline__ s16x8 lds_swz(const u16* base, int row, int cb) {
  const int addr = row * 128 + (cb ^ ((row & 7) << 4));
  return *(const s16x8*)((const char*)base + addr);
}

__global__ __launch_bounds__(256, 4) void attn_kernel(
    const u16* __restrict__ Qb, const u16* __restrict__ Kb,
    const u16* __restrict__ Vt, const int* __restrict__ mask,
    const float* __restrict__ rb, u16* __restrict__ AO)
{
  __shared__ float lut[2048];
  __shared__ __align__(16) u16 Ks[64 * 64];
  __shared__ __align__(16) u16 Vs[64 * 64];
  __shared__ __align__(16) u16 Ps[4][16 * 68];

  const int tid = threadIdx.x;
  const int lane = tid & 63;
  const int w = tid >> 6;
  const int bh = blockIdx.x;
  const int b = bh >> 4, h = bh & 15;
  const int q0 = blockIdx.y * 64 + w * 16;
  const int bS = b * S_, hh = h * 64;

  for (int idx = tid; idx < 2048; idx += 256) {
    const int rel = idx - 1024;
    const int ret = rel < 0 ? 16 : 0;
    const int n = rel < 0 ? -rel : rel;
    int bu;
    if (n < 8) bu = ret + n;
    else {
      const float t = logf((float)n * 0.125f) * (8.0f / 3.4657359027997265f);
      int vl = 8 + (int)t;
      if (vl > 15) vl = 15;
      bu = ret + vl;
    }
    lut[idx] = rb[bu * 16 + h] * 8.0f;
  }

  s16x8 qf[2];
#pragma unroll
  for (int kk = 0; kk < 2; kk++)
    qf[kk] = *(const s16x8*)(Qb + (size_t)(bS + q0 + (lane & 15)) * D_ + hh +
                             kk * 32 + (lane >> 4) * 8);

  f32x4 oacc[4];
#pragma unroll
  for (int i = 0; i < 4; i++) oacc[i] = {0.f, 0.f, 0.f, 0.f};
  float rm[4], rl[4];
#pragma unroll
  for (int j = 0; j < 4; j++) { rm[j] = -3e38f; rl[j] = 0.f; }

  for (int kt = 0; kt < S_; kt += 64) {
    __syncthreads();
#pragma unroll
    for (int i = 0; i < 2; i++) {
      const int flat = i * 4096 + w * 1024 + lane * 16;
      const int row = flat >> 7;
      const int ce = ((flat & 127) ^ ((row & 7) << 4)) >> 1;
      gload16(Kb + (size_t)(bS + kt + row) * D_ + hh + ce, Ks + i * 2048 + w * 512);
      gload16(Vt + (size_t)(bh * 64 + row) * S_ + kt + ce, Vs + i * 2048 + w * 512);
    }
    __syncthreads();

    f32x4 sacc[4];
#pragma unroll
    for (int i = 0; i < 4; i++) sacc[i] = {0.f, 0.f, 0.f, 0.f};
#pragma unroll
    for (int kk = 0; kk < 2; kk++) {
      const int cb = kk * 64 + (lane >> 4) * 16;
#pragma unroll
      for (int nf = 0; nf < 4; nf++) {
        const s16x8 kb = lds_swz(Ks, nf * 16 + (lane & 15), cb);
        sacc[nf] = mfma16(qf[kk], kb, sacc[nf]);
      }
    }

    int km[4];
#pragma unroll
    for (int nf = 0; nf < 4; nf++)
      km[nf] = mask[bS + kt + nf * 16 + (lane & 15)];

    const int lidx0 = q0 + (lane >> 4) * 4 + 1024 - kt - (lane & 15);
#pragma unroll
    for (int j = 0; j < 4; j++) {
      const int lrow = ((lane >> 4) << 2) + j;
      float sc[4];
      float mx = -3e38f;
#pragma unroll
      for (int nf = 0; nf < 4; nf++) {
        float s = (km[nf] == 0) ? -1e10f : sacc[nf][j];
        s += lut[lidx0 + j - nf * 16];
        sc[nf] = s;
        mx = fmaxf(mx, s);
      }
      mx = fmaxf(mx, __shfl_xor(mx, 1));
      mx = fmaxf(mx, __shfl_xor(mx, 2));
      mx = fmaxf(mx, __shfl_xor(mx, 4));
      mx = fmaxf(mx, __shfl_xor(mx, 8));
      const float m_new = fmaxf(rm[j], mx);
      const float fs = __expf(rm[j] - m_new);
      rm[j] = m_new;
      float psum = 0.f;
#pragma unroll
      for (int nf = 0; nf < 4; nf++) {
        const float p = __expf(sc[nf] - m_new);
        psum += p;
        Ps[w][lrow * 68 + nf * 16 + (lane & 15)] = f2bf(p);
      }
      psum += __shfl_xor(psum, 1);
      psum += __shfl_xor(psum, 2);
      psum += __shfl_xor(psum, 4);
      psum += __shfl_xor(psum, 8);
      rl[j] = rl[j] * fs + psum;
#pragma unroll
      for (int df = 0; df < 4; df++) oacc[df][j] *= fs;
    }

#pragma unroll
    for (int kk = 0; kk < 2; kk++) {
      const s16x8 pa = *(const s16x8*)&Ps[w][(lane & 15) * 68 + kk * 32 + (lane >> 4) * 8];
      const int cb = kk * 64 + (lane >> 4) * 16;
#pragma unroll
      for (int df = 0; df < 4; df++) {
        const s16x8 vb = lds_swz(Vs, df * 16 + (lane & 15), cb);
        oacc[df] = mfma16(pa, vb, oacc[df]);
      }
    }
  }

  float inv[4];
#pragma unroll
  for (int j = 0; j < 4; j++) inv[j] = 1.0f / rl[j];
#pragma unroll
  for (int df = 0; df < 4; df++)
#pragma unroll
    for (int j = 0; j < 4; j++) {
      const int qrow = q0 + ((lane >> 4) << 2) + j;
      AO[(size_t)(bS + qrow) * D_ + hh + df * 16 + (lane & 15)] =
          f2bf(oacc[df][j] * inv[j]);
    }
}

// ---------------- fused: Y = LN(X + P0 + P1 + bias) ------------------------
__global__ __launch_bounds__(256) void ln_fused2(
    const float* __restrict__ X, const float* __restrict__ P0,
    const float* __restrict__ P1, const float* __restrict__ bias,
    const float* __restrict__ g, const float* __restrict__ be,
    float* __restrict__ Yf, u16* __restrict__ Yh)
{
  const int row = blockIdx.x;
  const int tid = threadIdx.x;
  const size_t off = (size_t)row * D_;
  const float4 xv = ((const float4*)(X + off))[tid];
  const float4 p0 = ((const float4*)(P0 + off))[tid];
  const float4 p1 = ((const float4*)(P1 + off))[tid];
  const float4 bb = ((const float4*)bias)[tid];
  const float v0 = xv.x + p0.x + p1.x + bb.x;
  const float v1 = xv.y + p0.y + p1.y + bb.y;
  const float v2 = xv.z + p0.z + p1.z + bb.z;
  const float v3 = xv.w + p0.w + p1.w + bb.w;
  float sum = v0 + v1 + v2 + v3;
  float ss = v0 * v0 + v1 * v1 + v2 * v2 + v3 * v3;
#pragma unroll
  for (int o = 1; o < 64; o <<= 1) {
    sum += __shfl_xor(sum, o);
    ss += __shfl_xor(ss, o);
  }
  __shared__ float s1[4], s2[4];
  if ((tid & 63) == 0) { s1[tid >> 6] = sum; s2[tid >> 6] = ss; }
  __syncthreads();
  sum = s1[0] + s1[1] + s1[2] + s1[3];
  ss = s2[0] + s2[1] + s2[2] + s2[3];
  const float mu = sum * (1.f / D_);
  const float var = ss * (1.f / D_) - mu * mu;
  const float rstd = rsqrtf(var + 1e-5f);
  const float4 gv = ((const float4*)g)[tid];
  const float4 bv = ((const float4*)be)[tid];
  float4 y;
  y.x = (v0 - mu) * rstd * gv.x + bv.x;
  y.y = (v1 - mu) * rstd * gv.y + bv.y;
  y.z = (v2 - mu) * rstd * gv.z + bv.z;
  y.w = (v3 - mu) * rstd * gv.w + bv.w;
  ((float4*)(Yf + off))[tid] = y;
  u16x4 hv;
  hv.x = f2bf(y.x); hv.y = f2bf(y.y); hv.z = f2bf(y.z); hv.w = f2bf(y.w);
  ((u16x4*)(Yh + off))[tid] = hv;
}

// ---------------- embedding -------------------------------------------------
__global__ __launch_bounds__(256) void embed_kernel(
    const int* __restrict__ src, const float* __restrict__ tok,
    const float* __restrict__ pos, float* __restrict__ X, u16* __restrict__ Xh)
{
  const int row = blockIdx.x;
  const int s = row & (S_ - 1);
  const int t = src[row];
  const int tid = threadIdx.x;
  const float4 tv = ((const float4*)(tok + (size_t)t * D_))[tid];
  const float4 pv = ((const float4*)(pos + (size_t)s * D_))[tid];
  float4 y;
  y.x = tv.x * 32.f + pv.x;
  y.y = tv.y * 32.f + pv.y;
  y.z = tv.z * 32.f + pv.z;
  y.w = tv.w * 32.f + pv.w;
  ((float4*)(X + (size_t)row * D_))[tid] = y;
  u16x4 hv;
  hv.x = f2bf(y.x); hv.y = f2bf(y.y); hv.z = f2bf(y.z); hv.w = f2bf(y.w);
  ((u16x4*)(Xh + (size_t)row * D_))[tid] = hv;
}

// ---------------- launch ----------------------------------------------------
extern "C" void kernel_launch(void* const* d_in, const int* in_sizes, int n_in,
                              void* d_out, int out_size, void* d_ws, size_t ws_size,
                              hipStream_t stream)
{
  const int* src = (const int*)d_in[0];
  const int* mask = (const int*)d_in[1];
  const float* tok_emb = (const float*)d_in[2];
  const float* pos_emb = (const float*)d_in[3];
  const float* Wq = (const float*)d_in[4];
  const float* bq = (const float*)d_in[5];
  const float* Wk = (const float*)d_in[6];
  const float* bk = (const float*)d_in[7];
  const float* Wv = (const float*)d_in[8];
  const float* bv = (const float*)d_in[9];
  const float* Wo = (const float*)d_in[10];
  const float* bo = (const float*)d_in[11];
  const float* rb = (const float*)d_in[12];
  const float* g1 = (const float*)d_in[13];
  const float* b1n = (const float*)d_in[14];
  const float* W1 = (const float*)d_in[15];
  const float* b1f = (const float*)d_in[16];
  const float* W2 = (const float*)d_in[17];
  const float* b2f = (const float*)d_in[18];
  const float* g2 = (const float*)d_in[19];
  const float* b2n = (const float*)d_in[20];
  float* out = (float*)d_out;

  // ws map (120 MB peak):
  //   0-16  xb f32    16-24 xb16
  //  24-32 Qb16  32-40 Kb16  40-48 Vb16   (contiguous: fused-QKV out base)
  //  48-56 Vt16  56-64 AO16
  //  24-56 Hb16 (reuses dead Q/K/V/Vt region during FFN; 32MB)
  //  64-96 Pp (2x16MB f32 split-K partials)
  //  96-102 WTqkv  102-104 WTo  104-112 WT1  112-120 WT2
  char* ws = (char*)d_ws;
  const size_t MB = 1ull << 20;
  float* xb   = (float*)(ws + 0);
  u16*   xb16 = (u16*)(ws + 16 * MB);
  u16*   Qb16 = (u16*)(ws + 24 * MB);
  u16*   Kb16 = (u16*)(ws + 32 * MB);
  u16*   Vb16 = (u16*)(ws + 40 * MB);
  u16*   Vt16 = (u16*)(ws + 48 * MB);
  u16*   AO16 = (u16*)(ws + 56 * MB);
  float* Pp   = (float*)(ws + 64 * MB);
  u16*   WTqkv= (u16*)(ws + 96 * MB);
  u16*   WTo  = (u16*)(ws + 102 * MB);
  u16*   WT1  = (u16*)(ws + 104 * MB);
  u16*   WT2  = (u16*)(ws + 112 * MB);
  u16*   Hb16 = (u16*)(ws + 24 * MB);

  embed_kernel<<<M_, 256, 0, stream>>>(src, tok_emb, pos_emb, xb, xb16);

  for (int l = 0; l < L_; l++) {
    const size_t oDD = (size_t)l * D_ * D_;
    const size_t oDF = (size_t)l * D_ * F_;

    transpose4<<<dim3(32, 32, 4), 256, 0, stream>>>(
        Wq + oDD, Wk + oDD, Wv + oDD, Wo + oDD, WTqkv, WTo);
    transpose_cvt<<<dim3(F_ / 32, D_ / 32), 256, 0, stream>>>(W1 + oDF, WT1, D_, F_);
    transpose_cvt<<<dim3(D_ / 32, F_ / 32), 256, 0, stream>>>(W2 + oDF, WT2, F_, D_);

    gemm_qkvf<<<dim3(M_ / 128, 3 * D_ / 128), 256, 0, stream>>>(
        xb16, WTqkv, bq + l * D_, bk + l * D_, bv + l * D_, Qb16);

    vt_transpose<<<dim3(S_ / 64, B_ * H_), 256, 0, stream>>>(Vb16, Vt16);

    attn_kernel<<<dim3(B_ * H_, S_ / 64), 256, 0, stream>>>(
        Qb16, Kb16, Vt16, mask, rb + l * 32 * H_, AO16);

    gemm_splitk2<<<dim3(M_ / 128, D_ / 128, 2), 256, 0, stream>>>(
        AO16, WTo, Pp, D_, D_);

    ln_fused2<<<M_, 256, 0, stream>>>(
        xb, Pp, Pp + (size_t)M_ * D_, bo + l * D_,
        g1 + l * D_, b1n + l * D_, xb, xb16);

    gemm_ffn1<<<dim3(M_ / 256, F_ / 256), 512, 0, stream>>>(
        xb16, WT1, b1f + l * F_, Hb16);

    gemm_splitk2<<<dim3(M_ / 128, D_ / 128, 2), 256, 0, stream>>>(
        Hb16, WT2, Pp, D_, F_);

    ln_fused2<<<M_, 256, 0, stream>>>(
        xb, Pp, Pp + (size_t)M_ * D_, b2f + l * D_,
        g2 + l * D_, b2n + l * D_, (l == L_ - 1) ? out : xb, xb16);
  }
}